// Round 9
// baseline (109.801 us; speedup 1.0000x reference)
//
#include <hip/hip_runtime.h>

// Problem constants
#define NSEG   4480     // 70 * 64
#define ADIM   64
#define BDIM   16
#define NEDGE  65536
#define DPB    16       // destinations (output rows) per block
#define NBLK   (NSEG / DPB)   // 280 blocks; LDS 79.2 KB -> 2 blocks/CU, all resident
#define TPB    512      // 8 waves
#define CAP    64       // LDS bucket capacity per dst (Poisson mean 14.6, max ~35)
#define GSP    1092     // Gs pitch (bf16): 1088 + 4 pad
#define ALP    66       // atom-stage pitch (f32): 64 + 2 pad

// ONE dispatch, ZERO global intermediates. Cross-round fit (R4: F+L+52=111.4,
// R7: F+3L+47.8=112.3) gives L~2.6us/dispatch, F~57us fixed; R8's fused was
// still ~28us -- the remaining cost is the scatter->eb->fused global round
// trip through the poison-flushed cache hierarchy (eb/cnt re-read cold from
// HBM at ~900cyc) plus 2 extra dispatch boundaries. Here buckets live in LDS:
//   phase 0: streaming warm of atom+bond+kern+bias (6.2 MB, coalesced,
//            ~2.5 float4/thread, asm keep-alive) -> later random gathers hit
//            L3 (~200cyc) not HBM (~900cyc); overlaps with phase 1.
//   phase 1: scan pair[] (int4 = 2 edges/load, 64 iters unroll-8, L2-resident
//            stream), bucket {e,src} of mine into LDS (~230 LDS-atomic hits).
//   phase 2: R8's lane-parallel gather (proven 43->~29): per dst ONE pass
//            covers 16 edges; lane(q,p) loads atom[src_q, p*16..+16) +
//            bond[e_q, p*4..+4); atom tile transposed via LDS; bond broadcast
//            via v_readlane (compile-time lanes) -> SGPR FMA operand.
//            Exact f32 accum, single bf16 rounding into Gs.
//   phase 3: out[16,64] = Gs[16,1088] @ K2[1088,64], mfma_16x16x32_bf16,
//            K-split x2 + LDS reduce (proven R7/R8).
// LDS: bcnt 64 + ebuf 8192 + Gs 34944 + Al 33792 + pb 4096 = 81088 B.

typedef __bf16 bf16x8 __attribute__((ext_vector_type(8)));
typedef float  f32x4  __attribute__((ext_vector_type(4)));

__device__ __forceinline__ unsigned short f2bf(float f) {
    union { float f; unsigned int i; } c; c.f = f;
    unsigned int x = c.i;
    x += 0x7fffu + ((x >> 16) & 1u);   // round-to-nearest-even
    return (unsigned short)(x >> 16);
}

union U8 { unsigned short u[8]; bf16x8 v; };

__device__ __forceinline__ bf16x8 pack_bf8(float4 a, float4 b) {
    U8 r;
    r.u[0] = f2bf(a.x); r.u[1] = f2bf(a.y); r.u[2] = f2bf(a.z); r.u[3] = f2bf(a.w);
    r.u[4] = f2bf(b.x); r.u[5] = f2bf(b.y); r.u[6] = f2bf(b.z); r.u[7] = f2bf(b.w);
    return r.v;
}

// read lane l's copy of v (l compile-time-constant at every call site below)
__device__ __forceinline__ float rl(float v, int l) {
    return __builtin_bit_cast(float,
        __builtin_amdgcn_readlane(__builtin_bit_cast(int, v), l));
}

__global__ __launch_bounds__(TPB, 4) void fused_kernel(
    const float* __restrict__ atom,    // [4480, 64]  f32
    const float* __restrict__ bond,    // [65536, 16] f32
    const int*   __restrict__ pair,    // [65536, 2]  int32 {dst, src}
    const float* __restrict__ kern,    // [16, 4096]  f32
    const float* __restrict__ bias,    // [4096]      f32
    float*       __restrict__ out)     // [4480, 64]  f32
{
    __shared__ int  bcnt[DPB];
    __shared__ int2 ebuf[DPB][CAP];
    __shared__ unsigned short Gs[DPB * GSP];
    __shared__ float Al[8][16 * ALP];
    __shared__ f32x4 pb[4][64];

    const int t   = threadIdx.x;
    const int dlo = blockIdx.x * DPB;

    if (t < DPB) bcnt[t] = 0;

    // ---- phase 0: streaming cache warm (no barrier; overlaps phase 1) ---
    {
        float s = 0.f;
        const int g0 = blockIdx.x * TPB + t;
        const int gs = NBLK * TPB;                 // 143,360 threads
        const float4* a4 = (const float4*)atom;    // 71,680 float4
        const float4* b4 = (const float4*)bond;    // 262,144 float4
        const float4* k4 = (const float4*)kern;    // 16,384 float4
        const float4* s4 = (const float4*)bias;    // 1,024 float4
        for (int i = g0; i < 71680;  i += gs) { float4 v = a4[i]; s += v.x + v.y + v.z + v.w; }
        for (int i = g0; i < 262144; i += gs) { float4 v = b4[i]; s += v.x + v.y + v.z + v.w; }
        for (int i = g0; i < 16384;  i += gs) { float4 v = k4[i]; s += v.x + v.y + v.z + v.w; }
        if (g0 < 1024)                          { float4 v = s4[g0]; s += v.x + v.y + v.z + v.w; }
        __asm__ __volatile__("" :: "v"(s));        // keep loads live (rule #17)
    }
    __syncthreads();                               // bcnt zeros visible

    // ---- phase 1: scan pair[], bucket into LDS --------------------------
    {
        const int4* p4 = (const int4*)pair;        // {dst0,src0,dst1,src1}
#pragma unroll 8
        for (int i = 0; i < NEDGE / 2 / TPB; ++i) {     // 64 iters
            const int  ix4 = i * TPB + t;
            const int4 pp  = p4[ix4];
            const unsigned d0 = (unsigned)(pp.x - dlo);
            if (d0 < DPB) {
                const int ix = atomicAdd(&bcnt[d0], 1);
                if (ix < CAP) ebuf[d0][ix] = make_int2(2 * ix4, pp.y);
            }
            const unsigned d1 = (unsigned)(pp.z - dlo);
            if (d1 < DPB) {
                const int ix = atomicAdd(&bcnt[d1], 1);
                if (ix < CAP) ebuf[d1][ix] = make_int2(2 * ix4 + 1, pp.w);
            }
        }
    }
    __syncthreads();

    const int lane = t & 63;
    const int w    = t >> 6;                       // wave 0..7
    const int q    = lane >> 2;                    // edge slot within pass
    const int p    = lane & 3;                     // quarter of the atom row
    float* myAl = Al[w];

    // ---- phase 2: 2 dsts per wave, 16-edge lane-parallel passes ---------
#pragma unroll
    for (int half = 0; half < 2; ++half) {
        const int dl = 2 * w + half;
        int n = bcnt[dl]; n = n < CAP ? n : CAP;

        float g[17];
#pragma unroll
        for (int r = 0; r < 17; ++r) g[r] = 0.f;

        for (int kb = 0; kb < n; kb += 16) {
            const int  slot = kb + q;
            const bool val  = slot < n;
            const int2 es   = ebuf[dl][val ? slot : 0];   // slot 0 valid (n>=1 here)
            const float vs  = val ? 1.f : 0.f;

            // gather: 5 independent loads per lane, all in flight together
            const float* ap = atom + (size_t)es.y * ADIM + p * 16;
            float4 a0 = ((const float4*)ap)[0];
            float4 a1 = ((const float4*)ap)[1];
            float4 a2 = ((const float4*)ap)[2];
            float4 a3 = ((const float4*)ap)[3];
            const float4 bq = ((const float4*)(bond + (size_t)es.x * BDIM))[p];

            a0.x *= vs; a0.y *= vs; a0.z *= vs; a0.w *= vs;
            a1.x *= vs; a1.y *= vs; a1.z *= vs; a1.w *= vs;
            a2.x *= vs; a2.y *= vs; a2.z *= vs; a2.w *= vs;
            a3.x *= vs; a3.y *= vs; a3.z *= vs; a3.w *= vs;

            // stage atom tile: Al[q][p*16..+16)
            float* dst = myAl + q * ALP + p * 16;
            ((float4*)dst)[0] = a0;
            ((float4*)dst)[1] = a1;
            ((float4*)dst)[2] = a2;
            ((float4*)dst)[3] = a3;
            __asm__ __volatile__("s_waitcnt lgkmcnt(0)" ::: "memory");

            // accumulate: g[r] += bond[e_qq, r] * atom[src_qq][lane]
#pragma unroll
            for (int qq = 0; qq < 16; ++qq) {
                const float a = myAl[qq * ALP + lane];
                g[16] += a;                        // bias slice (scaled 0 if invalid)
#pragma unroll
                for (int pp = 0; pp < 4; ++pp) {
                    const int sl = 4 * qq + pp;    // compile-time constant
                    g[pp * 4 + 0] = fmaf(rl(bq.x, sl), a, g[pp * 4 + 0]);
                    g[pp * 4 + 1] = fmaf(rl(bq.y, sl), a, g[pp * 4 + 1]);
                    g[pp * 4 + 2] = fmaf(rl(bq.z, sl), a, g[pp * 4 + 2]);
                    g[pp * 4 + 3] = fmaf(rl(bq.w, sl), a, g[pp * 4 + 3]);
                }
            }
        }

        // lane j writes G[dl, r*64+j]: stride-1 u16 (2 lanes/bank, free)
#pragma unroll
        for (int r = 0; r < 17; ++r)
            Gs[dl * GSP + r * 64 + lane] = f2bf(g[r]);
    }
    __syncthreads();

    // ---- phase 3: out = Gs @ K2, K-split x2 (proven R7/R8) --------------
    // Fragment layouts (m89/m91-verified, passed R2-R8): A: row=lane&15,
    // k=quad*8+j; B: col=lane&15, k=quad*8+j; D: col=lane&15, row=quad*4+reg.
    {
        const int kh   = w >> 2;                   // K-half 0/1
        const int ct   = w & 3;                    // N tile 0..3
        const int m    = lane & 15;
        const int quad = lane >> 4;
        const int c    = ct * 16 + m;              // output col (B col n)
        const unsigned short* Ga = Gs + (size_t)m * GSP;
        const int rlo = kh ? 9 : 0;
        const int rhi = kh ? 17 : 9;               // slice 16 = bias

        f32x4 acc = {0.f, 0.f, 0.f, 0.f};

        const float* ks0 = ((rlo < 16) ? (kern + (size_t)rlo * 4096) : bias)
                           + (size_t)c * 64 + quad * 8;
        float4 x0 = *(const float4*)(ks0);
        float4 x1 = *(const float4*)(ks0 + 4);
        float4 y0 = *(const float4*)(ks0 + 32);
        float4 y1 = *(const float4*)(ks0 + 36);

        for (int r = rlo; r < rhi; ++r) {
            float4 nx0 = {}, nx1 = {}, ny0 = {}, ny1 = {};
            if (r + 1 < rhi) {                     // prefetch next slice
                const float* ns = ((r + 1 < 16) ? (kern + (size_t)(r + 1) * 4096)
                                                : bias)
                                  + (size_t)c * 64 + quad * 8;
                nx0 = *(const float4*)(ns);
                nx1 = *(const float4*)(ns + 4);
                ny0 = *(const float4*)(ns + 32);
                ny1 = *(const float4*)(ns + 36);
            }
            const bf16x8 a0 = *(const bf16x8*)(Ga + r * 64 + quad * 8);
            const bf16x8 a1 = *(const bf16x8*)(Ga + r * 64 + 32 + quad * 8);
            acc = __builtin_amdgcn_mfma_f32_16x16x32_bf16(a0, pack_bf8(x0, x1), acc, 0, 0, 0);
            acc = __builtin_amdgcn_mfma_f32_16x16x32_bf16(a1, pack_bf8(y0, y1), acc, 0, 0, 0);
            x0 = nx0; x1 = nx1; y0 = ny0; y1 = ny1;
        }

        if (kh) pb[ct][lane] = acc;                // upper-half partial
        __syncthreads();
        if (!kh) {
            const f32x4 pr = pb[ct][lane];
            acc[0] += pr[0]; acc[1] += pr[1]; acc[2] += pr[2]; acc[3] += pr[3];
            // D: row = dlo + quad*4 + rr, col = c. Every out element written.
#pragma unroll
            for (int rr = 0; rr < 4; ++rr)
                out[(size_t)(dlo + quad * 4 + rr) * ADIM + c] = acc[rr];
        }
    }
}

extern "C" void kernel_launch(void* const* d_in, const int* in_sizes, int n_in,
                              void* d_out, int out_size, void* d_ws, size_t ws_size,
                              hipStream_t stream) {
    const float* atom = (const float*)d_in[0];
    const float* bond = (const float*)d_in[1];
    const int*   pair = (const int*)  d_in[2];
    const float* kern = (const float*)d_in[3];
    const float* bias = (const float*)d_in[4];
    float* out = (float*)d_out;

    fused_kernel<<<NBLK, TPB, 0, stream>>>(atom, bond, pair, kern, bias, out);
}

// Round 10
// 98.357 us; speedup vs baseline: 1.1163x; 1.1163x over previous
//
#include <hip/hip_runtime.h>

// Problem constants
#define NSEG   4480     // 70 * 64
#define ADIM   64
#define BDIM   16
#define NEDGE  65536
#define DPB    16       // destinations (output rows) per fused block
#define NBLK   (NSEG / DPB)   // 280 blocks
#define TPB    512      // 8 waves
#define CAP    64       // bucket capacity per dst (Poisson mean 14.6, max ~35)
#define GSP    1092     // Gs pitch (bf16): 1088 + 4 pad
#define ALP    66       // atom-stage pitch (f32): 64 + 2 pad

// 3 plain dispatches (best-measured structure). Ledger after 10 rounds:
// harness-fixed ~54 us (poison fill 40.5 + ~6 restores; R9's 1-dispatch
// isolates it); in-kernel pair[] scans cost 25-55 us (R3/R4/R9) -> scatter
// stays edge-parallel in its own dispatch. R8's fused (~31 us) stalls 85%
// of its time (VALU 14%); the remaining serial head is 16 per-wave
// cold-HBM bucket reads per block. THIS round's single change: block-burst
// bucket prefetch -- all 512 threads load the block's 8 KB bucket region +
// 16 counters into LDS in ONE coalesced exposure; phase A reads LDS.
//
// Workspace: eb @ 0 : 4480*64*8 = 2,293,760 B {edge,src} buckets
//            cnt @ 4 MiB : 4480*4 B counters (memset each iteration)
#define CNT_OFF  (4u << 20)

typedef __bf16 bf16x8 __attribute__((ext_vector_type(8)));
typedef float  f32x4  __attribute__((ext_vector_type(4)));

__device__ __forceinline__ unsigned short f2bf(float f) {
    union { float f; unsigned int i; } c; c.f = f;
    unsigned int x = c.i;
    x += 0x7fffu + ((x >> 16) & 1u);   // round-to-nearest-even
    return (unsigned short)(x >> 16);
}

union U8 { unsigned short u[8]; bf16x8 v; };

__device__ __forceinline__ bf16x8 pack_bf8(float4 a, float4 b) {
    U8 r;
    r.u[0] = f2bf(a.x); r.u[1] = f2bf(a.y); r.u[2] = f2bf(a.z); r.u[3] = f2bf(a.w);
    r.u[4] = f2bf(b.x); r.u[5] = f2bf(b.y); r.u[6] = f2bf(b.z); r.u[7] = f2bf(b.w);
    return r.v;
}

// read lane l's copy of v (l compile-time-constant at every call site below)
__device__ __forceinline__ float rl(float v, int l) {
    return __builtin_bit_cast(float,
        __builtin_amdgcn_readlane(__builtin_bit_cast(int, v), l));
}

// ---------------------------------------------------------------------------
// scatter_kernel: edge-parallel bucketing (proven R5/R7/R8). One coalesced
// int2 load, one atomicAdd on the 17.9 KB L2-resident counter array, one
// 8 B bucket store. 65536 threads -> latency hidden by TLP.
// ---------------------------------------------------------------------------
__global__ __launch_bounds__(256) void scatter_kernel(
    const int* __restrict__ pair, int* __restrict__ cnt, int2* __restrict__ eb)
{
    const int e  = blockIdx.x * 256 + threadIdx.x;
    const int2 p = ((const int2*)pair)[e];          // .x = dst, .y = src
    const int idx = atomicAdd(&cnt[p.x], 1);
    if (idx < CAP) eb[(size_t)p.x * CAP + idx] = make_int2(e, p.y);
}

// ---------------------------------------------------------------------------
// fused_kernel:
//   prefetch: ONE coalesced burst loads the block's 16 buckets (8 KB; one
//     int4 per thread) + 16 counters into LDS -- replaces 16 serial
//     cold-HBM bucket reads per block (R8's dominant stall).
//   phase A (8 waves, 2 dsts each, pass = 16 edges; proven R8): lane(q,p)
//     loads atom[src_q, p*16..+16) + bond[e_q, p*4..+4) -- 5 independent
//     loads/lane, one latency exposure per dst; atom tile transposed via
//     LDS; bond broadcast via v_readlane (compile-time lanes) -> SGPR FMA.
//     Invalid slots clamp to bucket slot 0 (valid when n>=1) and scale 0.
//     Exact f32 accum, single bf16 rounding into Gs.
//   phase B (8 waves; proven R7/R8): out[16,64] = Gs[16,1088] @ K2[1088,64]
//     via mfma_16x16x32_bf16, K-split x2 (kh=w>>2) + LDS reduce,
//     software-pipelined B loads straight from kern/bias.
// Fragment layouts (m89/m91-verified, passed R2-R9): A: row=lane&15,
// k=quad*8+j; B: col=lane&15, k=quad*8+j; D: col=lane&15, row=quad*4+reg.
// LDS: bcnt 64 + ebuf 8192 + Gs 34944 + Al 33792 + pb 4096 = 81088 B
//   -> 2 blocks/CU (162176 <= 163840), 16 waves/CU.
// ---------------------------------------------------------------------------
__global__ __launch_bounds__(TPB, 4) void fused_kernel(
    const float* __restrict__ atom,    // [4480, 64]  f32
    const float* __restrict__ bond,    // [65536, 16] f32
    const int*   __restrict__ cnt,     // [4480]
    const int2*  __restrict__ eb,      // [4480, 64] {edge, src}
    const float* __restrict__ kern,    // [16, 4096]  f32
    const float* __restrict__ bias,    // [4096]      f32
    float*       __restrict__ out)     // [4480, 64]  f32
{
    __shared__ int  bcnt[DPB];
    __shared__ int2 ebuf[DPB][CAP];
    __shared__ unsigned short Gs[DPB * GSP];
    __shared__ float Al[8][16 * ALP];
    __shared__ f32x4 pb[4][64];

    const int t   = threadIdx.x;
    const int dlo = blockIdx.x * DPB;

    // ---- bucket burst prefetch: 8 KB + counters in ONE exposure ---------
    {
        const int4* src = (const int4*)(eb + (size_t)dlo * CAP);  // 512 int4
        ((int4*)ebuf)[t] = src[t];
        if (t < DPB) bcnt[t] = cnt[dlo + t];
    }
    __syncthreads();

    const int lane = t & 63;
    const int w    = t >> 6;                       // wave 0..7
    const int q    = lane >> 2;                    // edge slot within pass
    const int p    = lane & 3;                     // quarter of the atom row
    float* myAl = Al[w];

    // ---- phase A: 2 dsts per wave, 16-edge lane-parallel passes ---------
#pragma unroll
    for (int half = 0; half < 2; ++half) {
        const int dl = 2 * w + half;
        int n = bcnt[dl]; n = n < CAP ? n : CAP;

        float g[17];
#pragma unroll
        for (int r = 0; r < 17; ++r) g[r] = 0.f;

        for (int kb = 0; kb < n; kb += 16) {
            const int  slot = kb + q;
            const bool val  = slot < n;
            const int2 es   = ebuf[dl][val ? slot : 0];  // slot 0 valid (n>=1 here)
            const float vs  = val ? 1.f : 0.f;

            // gather: 5 independent loads per lane, all in flight together
            const float* ap = atom + (size_t)es.y * ADIM + p * 16;
            float4 a0 = ((const float4*)ap)[0];
            float4 a1 = ((const float4*)ap)[1];
            float4 a2 = ((const float4*)ap)[2];
            float4 a3 = ((const float4*)ap)[3];
            const float4 bq = ((const float4*)(bond + (size_t)es.x * BDIM))[p];

            a0.x *= vs; a0.y *= vs; a0.z *= vs; a0.w *= vs;
            a1.x *= vs; a1.y *= vs; a1.z *= vs; a1.w *= vs;
            a2.x *= vs; a2.y *= vs; a2.z *= vs; a2.w *= vs;
            a3.x *= vs; a3.y *= vs; a3.z *= vs; a3.w *= vs;

            // stage atom tile: Al[q][p*16..+16)
            float* dst = myAl + q * ALP + p * 16;
            ((float4*)dst)[0] = a0;
            ((float4*)dst)[1] = a1;
            ((float4*)dst)[2] = a2;
            ((float4*)dst)[3] = a3;
            __asm__ __volatile__("s_waitcnt lgkmcnt(0)" ::: "memory");

            // accumulate: g[r] += bond[e_qq, r] * atom[src_qq][lane]
#pragma unroll
            for (int qq = 0; qq < 16; ++qq) {
                const float a = myAl[qq * ALP + lane];
                g[16] += a;                        // bias slice (scaled 0 if invalid)
#pragma unroll
                for (int pp = 0; pp < 4; ++pp) {
                    const int sl = 4 * qq + pp;    // compile-time constant
                    g[pp * 4 + 0] = fmaf(rl(bq.x, sl), a, g[pp * 4 + 0]);
                    g[pp * 4 + 1] = fmaf(rl(bq.y, sl), a, g[pp * 4 + 1]);
                    g[pp * 4 + 2] = fmaf(rl(bq.z, sl), a, g[pp * 4 + 2]);
                    g[pp * 4 + 3] = fmaf(rl(bq.w, sl), a, g[pp * 4 + 3]);
                }
            }
        }

        // lane j writes G[dl, r*64+j]: stride-1 u16 (2 lanes/bank, free)
#pragma unroll
        for (int r = 0; r < 17; ++r)
            Gs[dl * GSP + r * 64 + lane] = f2bf(g[r]);
    }
    __syncthreads();

    // ---- phase B: out = Gs @ K2, K-split x2 (proven R7/R8) --------------
    {
        const int kh   = w >> 2;                   // K-half 0/1
        const int ct   = w & 3;                    // N tile 0..3
        const int m    = lane & 15;
        const int quad = lane >> 4;
        const int c    = ct * 16 + m;              // output col (B col n)
        const unsigned short* Ga = Gs + (size_t)m * GSP;
        const int rlo = kh ? 9 : 0;
        const int rhi = kh ? 17 : 9;               // slice 16 = bias

        f32x4 acc = {0.f, 0.f, 0.f, 0.f};

        const float* ks0 = ((rlo < 16) ? (kern + (size_t)rlo * 4096) : bias)
                           + (size_t)c * 64 + quad * 8;
        float4 x0 = *(const float4*)(ks0);
        float4 x1 = *(const float4*)(ks0 + 4);
        float4 y0 = *(const float4*)(ks0 + 32);
        float4 y1 = *(const float4*)(ks0 + 36);

        for (int r = rlo; r < rhi; ++r) {
            float4 nx0 = {}, nx1 = {}, ny0 = {}, ny1 = {};
            if (r + 1 < rhi) {                     // prefetch next slice
                const float* ns = ((r + 1 < 16) ? (kern + (size_t)(r + 1) * 4096)
                                                : bias)
                                  + (size_t)c * 64 + quad * 8;
                nx0 = *(const float4*)(ns);
                nx1 = *(const float4*)(ns + 4);
                ny0 = *(const float4*)(ns + 32);
                ny1 = *(const float4*)(ns + 36);
            }
            const bf16x8 a0 = *(const bf16x8*)(Ga + r * 64 + quad * 8);
            const bf16x8 a1 = *(const bf16x8*)(Ga + r * 64 + 32 + quad * 8);
            acc = __builtin_amdgcn_mfma_f32_16x16x32_bf16(a0, pack_bf8(x0, x1), acc, 0, 0, 0);
            acc = __builtin_amdgcn_mfma_f32_16x16x32_bf16(a1, pack_bf8(y0, y1), acc, 0, 0, 0);
            x0 = nx0; x1 = nx1; y0 = ny0; y1 = ny1;
        }

        if (kh) pb[ct][lane] = acc;                // upper-half partial
        __syncthreads();
        if (!kh) {
            const f32x4 pr = pb[ct][lane];
            acc[0] += pr[0]; acc[1] += pr[1]; acc[2] += pr[2]; acc[3] += pr[3];
            // D: row = dlo + quad*4 + rr, col = c. Every out element written.
#pragma unroll
            for (int rr = 0; rr < 4; ++rr)
                out[(size_t)(dlo + quad * 4 + rr) * ADIM + c] = acc[rr];
        }
    }
}

extern "C" void kernel_launch(void* const* d_in, const int* in_sizes, int n_in,
                              void* d_out, int out_size, void* d_ws, size_t ws_size,
                              hipStream_t stream) {
    const float* atom = (const float*)d_in[0];
    const float* bond = (const float*)d_in[1];
    const int*   pair = (const int*)  d_in[2];
    const float* kern = (const float*)d_in[3];
    const float* bias = (const float*)d_in[4];
    float* out = (float*)d_out;

    int2* eb  = (int2*)d_ws;                         // 2.29 MB buckets
    int*  cnt = (int*)((char*)d_ws + CNT_OFF);       // 17.9 KB counters

    hipMemsetAsync(cnt, 0, NSEG * sizeof(int), stream);
    scatter_kernel<<<NEDGE / 256, 256, 0, stream>>>(pair, cnt, eb);
    fused_kernel<<<NBLK, TPB, 0, stream>>>(atom, bond, cnt, eb, kern, bias, out);
}